// Round 4
// baseline (261.248 us; speedup 1.0000x reference)
//
#include <hip/hip_runtime.h>

#define D 128
#define NROW 50000      // N_U == N_V == 50000
#define NEDGE 640000
#define CAP 64          // ELL row capacity; P(Poisson(12.8) >= 64) ~ 3e-23/row

// edge routing geometry
#define RBLK 160        // route blocks; 160*4000 == 640000
#define EPB  4000       // edges per route block
#define NBKT 196        // row buckets of 256 rows: ceil(50000/256)
#define CELL 64         // per-(bucket, route-block) record capacity

typedef __attribute__((ext_vector_type(8))) short short8;
typedef __attribute__((ext_vector_type(4))) float f32x4;

__device__ __forceinline__ unsigned short f2bf(float f) {
    unsigned u = __float_as_uint(f);
    unsigned r = (u + 0x7fff + ((u >> 16) & 1)) >> 16;  // round-nearest-even
    return (unsigned short)r;
}
// accumulate packed bf16 pair (lo->e, hi->o)
__device__ __forceinline__ void acc2(float& e, float& o, unsigned g) {
    e += __uint_as_float(g << 16);
    o += __uint_as_float(g & 0xffff0000u);
}

// ============================================================
// K1 route_cvt_gemm1:
//   [0,65)     small_gemm1: T (130x128) = [W0; b0; b1] @ W1
//   [65,225)   route: bucket edges by row>>8 into per-(bucket,block)
//              segments via LDS atomics; coalesced 256B segment writes
//   [225,6475) cvt_bf16: B1 = bf16(X_v)  (fills CUs idle during route)
// ============================================================
__global__ __launch_bounds__(256) void route_cvt_gemm1(const int* __restrict__ eu,
                                                       const int* __restrict__ ev,
                                                       unsigned int* __restrict__ recbuf_u,
                                                       int* __restrict__ counts_u,
                                                       unsigned int* __restrict__ recbuf_v,
                                                       int* __restrict__ counts_v,
                                                       const float4* __restrict__ Xv4,
                                                       ushort4* __restrict__ Xb4,
                                                       const float* __restrict__ W0,
                                                       const float* __restrict__ b0,
                                                       const float* __restrict__ b1,
                                                       const float* __restrict__ W1,
                                                       float* __restrict__ T) {
    const int blk = blockIdx.x, tid = threadIdx.x;
    if (blk < 65) {                   // small_gemm1
        __shared__ float R[2][128];
        int sub = tid >> 7, j = tid & 127;
        int i = blk * 2 + sub;
        bool valid = (i < 130);
        const float* row = nullptr;
        if (valid && i < 128) row = W0 + i * D;
        else if (valid && i == 128) row = b0;
        R[sub][j] = row ? row[j] : 0.f;
        __syncthreads();
        if (!valid) return;
        if (i == 129) { T[129 * D + j] = b1[j]; return; }
        float acc = 0.f;
#pragma unroll 8
        for (int k = 0; k < 128; k++) acc += R[sub][k] * W1[k * D + j];
        T[i * D + j] = acc;
    } else if (blk < 225) {           // route
        __shared__ int cnt_s[NBKT];
        __shared__ unsigned int rec_s[NBKT * CELL];   // 49 KB
        const int rblk = blk - 65;
        const int base = rblk * EPB;
        for (int dir = 0; dir < 2; dir++) {
            const int* __restrict__ kk = dir ? ev : eu;   // key (destination row)
            const int* __restrict__ pp = dir ? eu : ev;   // payload (source row)
            unsigned int* __restrict__ recbuf = dir ? recbuf_v : recbuf_u;
            int* __restrict__ counts = dir ? counts_v : counts_u;
            if (tid < NBKT) cnt_s[tid] = 0;
            __syncthreads();
            for (int e0 = tid; e0 < EPB; e0 += 256) {
                int e = base + e0;
                int key = kk[e], pay = pp[e];
                int k = key >> 8;
                int p = atomicAdd(&cnt_s[k], 1);          // LDS atomic
                if (p < CELL) rec_s[k * CELL + p] = ((unsigned)key << 16) | (unsigned)pay;
            }
            __syncthreads();
            if (tid < NBKT) {
                int c = cnt_s[tid];
                counts[rblk * NBKT + tid] = (c < CELL) ? c : CELL;
            }
            const int wave = tid >> 6, lane = tid & 63;
            for (int k = wave; k < NBKT; k += 4) {        // 49 segments/wave
                int c = cnt_s[k]; c = (c < CELL) ? c : CELL;
                if (lane < c)
                    recbuf[(size_t)(k * RBLK + rblk) * CELL + lane] = rec_s[k * CELL + lane];
            }
            __syncthreads();
        }
    } else {                          // cvt: n4 = 1,600,000 = 6250*256 exactly
        int i = (blk - 225) * 256 + tid;
        float4 v = Xv4[i];
        ushort4 o;
        o.x = f2bf(v.x); o.y = f2bf(v.y); o.z = f2bf(v.z); o.w = f2bf(v.w);
        Xb4[i] = o;
    }
}

// ============================================================
// K2: ELL build (blocks [0,392)) + sg2 ([392,457))
// ============================================================
__global__ __launch_bounds__(256) void ellbuild_sg2(const unsigned int* __restrict__ recbuf_u,
                                                    const int* __restrict__ counts_u,
                                                    const unsigned int* __restrict__ recbuf_v,
                                                    const int* __restrict__ counts_v,
                                                    unsigned short* __restrict__ ell_u,
                                                    int* __restrict__ cnt_u,
                                                    unsigned short* __restrict__ ell_v,
                                                    int* __restrict__ cnt_v,
                                                    const float* __restrict__ T,
                                                    const float* __restrict__ W2,
                                                    float* __restrict__ P,
                                                    unsigned short* __restrict__ PbT) {
    const int blk = blockIdx.x, tid = threadIdx.x;
    if (blk < 2 * NBKT) {
        const int dir = (blk >= NBKT) ? 1 : 0;
        const int k = dir ? blk - NBKT : blk;
        const unsigned int* __restrict__ recbuf = dir ? recbuf_v : recbuf_u;
        const int* __restrict__ counts = dir ? counts_v : counts_u;
        unsigned short* __restrict__ ell = dir ? ell_v : ell_u;
        int* __restrict__ cnt = dir ? cnt_v : cnt_u;

        __shared__ __align__(16) unsigned short ell_s[256 * CAP];  // 32 KB
        __shared__ int cnt_s[256];
        __shared__ int seg_c[RBLK];
        cnt_s[tid] = 0;
        if (tid < RBLK) seg_c[tid] = counts[tid * NBKT + k];
        __syncthreads();

        const int wave = tid >> 6, lane = tid & 63;
        const unsigned int* rb = recbuf + (size_t)k * RBLK * CELL;
        int b = wave;
        int c0 = seg_c[b];
        unsigned int r0 = 0;
        if (lane < c0) r0 = rb[b * CELL + lane];
        while (b < RBLK) {
            int bn = b + 4;
            int c1 = 0; unsigned int r1 = 0;
            if (bn < RBLK) { c1 = seg_c[bn]; if (lane < c1) r1 = rb[bn * CELL + lane]; }
            if (lane < c0) {
                int lr = (r0 >> 16) & 255;                 // row within bucket
                int p = atomicAdd(&cnt_s[lr], 1);          // LDS atomic (exact degree)
                if (p < CAP) ell_s[lr * CAP + p] = (unsigned short)(r0 & 0xffff);
            }
            b = bn; c0 = c1; r0 = r1;
        }
        __syncthreads();
        const int row0 = k << 8;
        const int nrows = (row0 + 256 <= NROW) ? 256 : (NROW - row0);  // bucket 195: 80
        const uint4* src = (const uint4*)ell_s;
        uint4* dst = (uint4*)(ell + (size_t)row0 * CAP);
        for (int i = tid; i < nrows * 8; i += 256) dst[i] = src[i];    // coalesced 128B rows
        if (tid < nrows) cnt[row0 + tid] = cnt_s[tid];
    } else {                              // small_gemm2: P = T @ W2, PbT = bf16(P^T)
        __shared__ float R[2][128];
        int idx = blk - 2 * NBKT;
        int sub = tid >> 7, j = tid & 127;
        int i = idx * 2 + sub;
        bool valid = (i < 130);
        R[sub][j] = valid ? T[i * D + j] : 0.f;
        __syncthreads();
        if (!valid) return;
        float acc = 0.f;
#pragma unroll 8
        for (int kk = 0; kk < 128; kk++) acc += R[sub][kk] * W2[kk * D + j];
        P[i * D + j] = acc;
        if (i < 128) PbT[j * 128 + i] = f2bf(acc);
    }
}

// ============================================================
// gather core: one 16B output chunk (8 bf16 lanes) of
// sum_{s in idx[0..n)} A[s]. Ac = A + c*8 (chunk-offset base).
// Index reads vectorized (uint4 = 8 indices), 8 data loads in flight.
// ============================================================
__device__ __forceinline__ uint4 gather_chunk(const unsigned short* __restrict__ Ac,
                                              const unsigned short* __restrict__ idx,
                                              int n) {
    float a0 = 0.f, a1 = 0.f, a2 = 0.f, a3 = 0.f, a4 = 0.f, a5 = 0.f, a6 = 0.f, a7 = 0.f;
    int i = 0;
    for (; i + 8 <= n; i += 8) {
        uint4 iv = *(const uint4*)(idx + i);         // 8 indices, one load (16B aligned)
        uint4 q0 = *(const uint4*)(Ac + (size_t)(iv.x & 0xffffu) * D);
        uint4 q1 = *(const uint4*)(Ac + (size_t)(iv.x >> 16) * D);
        uint4 q2 = *(const uint4*)(Ac + (size_t)(iv.y & 0xffffu) * D);
        uint4 q3 = *(const uint4*)(Ac + (size_t)(iv.y >> 16) * D);
        uint4 q4 = *(const uint4*)(Ac + (size_t)(iv.z & 0xffffu) * D);
        uint4 q5 = *(const uint4*)(Ac + (size_t)(iv.z >> 16) * D);
        uint4 q6 = *(const uint4*)(Ac + (size_t)(iv.w & 0xffffu) * D);
        uint4 q7 = *(const uint4*)(Ac + (size_t)(iv.w >> 16) * D);
        acc2(a0, a1, q0.x); acc2(a2, a3, q0.y); acc2(a4, a5, q0.z); acc2(a6, a7, q0.w);
        acc2(a0, a1, q1.x); acc2(a2, a3, q1.y); acc2(a4, a5, q1.z); acc2(a6, a7, q1.w);
        acc2(a0, a1, q2.x); acc2(a2, a3, q2.y); acc2(a4, a5, q2.z); acc2(a6, a7, q2.w);
        acc2(a0, a1, q3.x); acc2(a2, a3, q3.y); acc2(a4, a5, q3.z); acc2(a6, a7, q3.w);
        acc2(a0, a1, q4.x); acc2(a2, a3, q4.y); acc2(a4, a5, q4.z); acc2(a6, a7, q4.w);
        acc2(a0, a1, q5.x); acc2(a2, a3, q5.y); acc2(a4, a5, q5.z); acc2(a6, a7, q5.w);
        acc2(a0, a1, q6.x); acc2(a2, a3, q6.y); acc2(a4, a5, q6.z); acc2(a6, a7, q6.w);
        acc2(a0, a1, q7.x); acc2(a2, a3, q7.y); acc2(a4, a5, q7.z); acc2(a6, a7, q7.w);
    }
    if (i + 4 <= n) {
        uint2 iv = *(const uint2*)(idx + i);         // 4 indices (8B aligned: i%8==0)
        uint4 q0 = *(const uint4*)(Ac + (size_t)(iv.x & 0xffffu) * D);
        uint4 q1 = *(const uint4*)(Ac + (size_t)(iv.x >> 16) * D);
        uint4 q2 = *(const uint4*)(Ac + (size_t)(iv.y & 0xffffu) * D);
        uint4 q3 = *(const uint4*)(Ac + (size_t)(iv.y >> 16) * D);
        acc2(a0, a1, q0.x); acc2(a2, a3, q0.y); acc2(a4, a5, q0.z); acc2(a6, a7, q0.w);
        acc2(a0, a1, q1.x); acc2(a2, a3, q1.y); acc2(a4, a5, q1.z); acc2(a6, a7, q1.w);
        acc2(a0, a1, q2.x); acc2(a2, a3, q2.y); acc2(a4, a5, q2.z); acc2(a6, a7, q2.w);
        acc2(a0, a1, q3.x); acc2(a2, a3, q3.y); acc2(a4, a5, q3.z); acc2(a6, a7, q3.w);
        i += 4;
    }
    for (; i < n; i++) {
        uint4 q0 = *(const uint4*)(Ac + (size_t)idx[i] * D);
        acc2(a0, a1, q0.x); acc2(a2, a3, q0.y); acc2(a4, a5, q0.z); acc2(a6, a7, q0.w);
    }
    uint4 o;
    o.x = (unsigned)f2bf(a0) | ((unsigned)f2bf(a1) << 16);
    o.y = (unsigned)f2bf(a2) | ((unsigned)f2bf(a3) << 16);
    o.z = (unsigned)f2bf(a4) | ((unsigned)f2bf(a5) << 16);
    o.w = (unsigned)f2bf(a6) | ((unsigned)f2bf(a7) << 16);
    return o;
}

// subwave-16 gather to global: OUTb[r] = bf16( sum_{s in ELL[r]} A[s] )
__device__ __forceinline__ void gather_body(const unsigned short* __restrict__ A,
                                            const int* __restrict__ cnt,
                                            const unsigned short* __restrict__ ell,
                                            unsigned short* __restrict__ OUTb,
                                            int blk) {
    const int r = blk * 16 + (threadIdx.x >> 4);    // 50000 % 16 == 0
    const int c = threadIdx.x & 15;                  // 16B chunk within row
    int n = cnt[r]; n = (n < CAP) ? n : CAP;
    uint4 o = gather_chunk(A + c * 8, ell + (size_t)r * CAP, n);
    *(uint4*)(OUTb + (size_t)r * D + c * 8) = o;
}

__device__ __forceinline__ void tk_body(const int* __restrict__ cnt_v,
                                        const unsigned short* __restrict__ ell_v,
                                        const int* __restrict__ cnt_u,
                                        int* __restrict__ t, int v) {
    if (v >= NROW) return;
    int n = cnt_v[v]; n = (n < CAP) ? n : CAP;
    const unsigned short* row = ell_v + (size_t)v * CAP;
    int s = 0;
    for (int i = 0; i < n; i += 8) {
        uint4 iv = *(const uint4*)(row + i);     // safe: row has CAP=64 entries
        unsigned sx[8] = {iv.x & 0xffffu, iv.x >> 16, iv.y & 0xffffu, iv.y >> 16,
                          iv.z & 0xffffu, iv.z >> 16, iv.w & 0xffffu, iv.w >> 16};
#pragma unroll
        for (int j = 0; j < 8; j++) if (i + j < n) s += cnt_u[sx[j]];
    }
    t[v] = s;
}

__device__ __forceinline__ void g23_body(const int* __restrict__ cnt_u,
                                         const unsigned short* __restrict__ ell_u,
                                         const int* __restrict__ cnt_v,
                                         const int* __restrict__ t,
                                         int* __restrict__ g2, int* __restrict__ g3, int u) {
    if (u >= NROW) return;
    int n = cnt_u[u]; n = (n < CAP) ? n : CAP;
    const unsigned short* row = ell_u + (size_t)u * CAP;
    int a = 0, b = 0;
    for (int i = 0; i < n; i += 8) {
        uint4 iv = *(const uint4*)(row + i);
        unsigned sx[8] = {iv.x & 0xffffu, iv.x >> 16, iv.y & 0xffffu, iv.y >> 16,
                          iv.z & 0xffffu, iv.z >> 16, iv.w & 0xffffu, iv.w >> 16};
#pragma unroll
        for (int j = 0; j < 8; j++)
            if (i + j < n) { a += t[sx[j]]; b += cnt_v[sx[j]]; }
    }
    g2[u] = a;
    g3[u] = b;
}

// K3: hop 1 (v2u) + t_k
__global__ __launch_bounds__(256) void gather1_tk(const unsigned short* __restrict__ A,
                                                  const int* __restrict__ cnt_u,
                                                  const unsigned short* __restrict__ ell_u,
                                                  unsigned short* __restrict__ OUTb,
                                                  const int* __restrict__ cnt_v,
                                                  const unsigned short* __restrict__ ell_v,
                                                  int* __restrict__ t) {
    if (blockIdx.x < 3125) gather_body(A, cnt_u, ell_u, OUTb, blockIdx.x);
    else tk_body(cnt_v, ell_v, cnt_u, t, (blockIdx.x - 3125) * 256 + threadIdx.x);
}

// K4: hop 2 (u2v) + g23
__global__ __launch_bounds__(256) void gather2_g23(const unsigned short* __restrict__ A,
                                                   const int* __restrict__ cnt_v,
                                                   const unsigned short* __restrict__ ell_v,
                                                   unsigned short* __restrict__ OUTb,
                                                   const int* __restrict__ cnt_u,
                                                   const unsigned short* __restrict__ ell_u,
                                                   const int* __restrict__ t,
                                                   int* __restrict__ g2, int* __restrict__ g3) {
    if (blockIdx.x < 3125) gather_body(A, cnt_v, ell_v, OUTb, blockIdx.x);
    else g23_body(cnt_u, ell_u, cnt_v, t, g2, g3, (blockIdx.x - 3125) * 256 + threadIdx.x);
}

// ============================================================
// K5: fused hop 3 (v2u) + MFMA final GEMM + rank-3 fp32 bias epilogue.
// Block = 64 output rows: gather into LDS (272B row stride -> b128 reads
// at the 8-lane/4-bank-group floor, conflict-free), barrier, MFMA.
// Saves the 12.8 MB A write + 12.8 MB re-read and one dispatch boundary.
// OUT[r][j] = (Z @ W0W1W2)[r][j] + g2[r]*c0[j] + g3[r]*c1[j] + du[r]*b2[j]
// ============================================================
#define LSTRIDE 136   // ushorts per LDS row = 17 * 8 (272 B)

__global__ __launch_bounds__(256) void gather3_gemm(const unsigned short* __restrict__ B2,
                                                    const int* __restrict__ cnt_u,
                                                    const unsigned short* __restrict__ ell_u,
                                                    const unsigned short* __restrict__ PbT,
                                                    const float* __restrict__ P,
                                                    const float* __restrict__ b2,
                                                    const int* __restrict__ g2,
                                                    const int* __restrict__ g3,
                                                    const int* __restrict__ du,
                                                    float* __restrict__ OUT) {
    __shared__ __align__(16) unsigned short Asm[64 * LSTRIDE];   // 17.4 KB
    const int tid = threadIdx.x;
    const int m0blk = blockIdx.x * 64;

    // ---- phase 1: gather this block's 64 rows (bf16) into LDS ----
    const int c = tid & 15;
#pragma unroll 1
    for (int it = 0; it < 4; it++) {
        int rl = (tid >> 4) + it * 16;           // 0..63
        int r = m0blk + rl;
        uint4 o = {0u, 0u, 0u, 0u};
        if (r < NROW) {
            int n = cnt_u[r]; n = (n < CAP) ? n : CAP;
            o = gather_chunk(B2 + c * 8, ell_u + (size_t)r * CAP, n);
        }
        *(uint4*)(Asm + rl * LSTRIDE + c * 8) = o;
    }
    __syncthreads();

    // ---- phase 2: per-wave 16x128 MFMA tile ----
    const int wave = tid >> 6;
    const int lane = tid & 63;
    const int ml = lane & 15;      // m (A-row / D-col) index
    const int quad = lane >> 4;    // k-quad / D-row-quad
    const int m0 = m0blk + wave * 16;
    if (m0 >= NROW) return;        // block 781: waves 1..3 idle (after barrier)

    const uint4* zr = (const uint4*)(Asm + (size_t)(wave * 16 + ml) * LSTRIDE);

    f32x4 acc[8];
#pragma unroll
    for (int nt = 0; nt < 8; nt++) acc[nt] = (f32x4){0.f, 0.f, 0.f, 0.f};

#pragma unroll
    for (int kc = 0; kc < 4; kc++) {
        short8 a = __builtin_bit_cast(short8, zr[kc * 4 + quad]);
#pragma unroll
        for (int nt = 0; nt < 8; nt++) {
            const uint4* br = (const uint4*)(PbT + (size_t)(nt * 16 + ml) * D);
            short8 b = __builtin_bit_cast(short8, br[kc * 4 + quad]);
            acc[nt] = __builtin_amdgcn_mfma_f32_16x16x32_bf16(a, b, acc[nt], 0, 0, 0);
        }
    }

    float sg2[4], sg3[4], sdu[4];
#pragma unroll
    for (int reg = 0; reg < 4; reg++) {
        int r = m0 + quad * 4 + reg;            // < NROW (tail block: wave 0 covers 49984..49999)
        sg2[reg] = (float)g2[r];
        sg3[reg] = (float)g3[r];
        sdu[reg] = (float)du[r];
    }
    const float* c0 = P + 128 * D;
    const float* c1 = P + 129 * D;
#pragma unroll
    for (int nt = 0; nt < 8; nt++) {
        int col = nt * 16 + ml;
        float cc0 = c0[col], cc1 = c1[col], cb2 = b2[col];
#pragma unroll
        for (int reg = 0; reg < 4; reg++) {
            int r = m0 + quad * 4 + reg;
            OUT[(size_t)r * D + col] = acc[nt][reg] + sg2[reg] * cc0 + sg3[reg] * cc1 + sdu[reg] * cb2;
        }
    }
}

// ============================================================
extern "C" void kernel_launch(void* const* d_in, const int* in_sizes, int n_in,
                              void* d_out, int out_size, void* d_ws, size_t ws_size,
                              hipStream_t stream) {
    // 0=X_u(unused), 1=X_v, 2=edge_u, 3=edge_v, 4=W0, 5=b0, 6=W1, 7=b1, 8=W2, 9=b2
    const float* X_v = (const float*)d_in[1];
    const int* edge_u = (const int*)d_in[2];
    const int* edge_v = (const int*)d_in[3];
    const float* W0 = (const float*)d_in[4];
    const float* b0 = (const float*)d_in[5];
    const float* W1 = (const float*)d_in[6];
    const float* b1 = (const float*)d_in[7];
    const float* W2 = (const float*)d_in[8];
    const float* b2 = (const float*)d_in[9];

    // ---- ws layout (~43.1 MB) ----
    char* w = (char*)d_ws;
    unsigned short* A = (unsigned short*)w;                    // bf16 [NROW x 128] = 12.8 MB
    unsigned short* ell_u = (unsigned short*)(w + 12800000);   // NROW*CAP ushort = 6.4 MB
    unsigned short* ell_v = ell_u + (size_t)NROW * CAP;        // 6.4 MB
    int* cnt_u = (int*)(ell_v + (size_t)NROW * CAP);           // 50000 (exact degrees)
    int* cnt_v = cnt_u + NROW;                                 // 50000
    int* tbuf  = cnt_v + NROW;                                 // 50000
    int* g2    = tbuf + NROW;                                  // 50000
    int* g3    = g2 + NROW;                                    // 50000
    float* T   = (float*)(g3 + NROW);                          // 130*128
    float* P   = T + 130 * D;                                  // 130*128
    unsigned short* PbT = (unsigned short*)(P + 130 * D);      // 128*128 bf16
    unsigned int* recbuf_u = (unsigned int*)(PbT + 128 * 128); // 196*160*64 u32 = 8.03 MB
    unsigned int* recbuf_v = recbuf_u + (size_t)NBKT * RBLK * CELL;  // 8.03 MB
    int* counts_u = (int*)(recbuf_v + (size_t)NBKT * RBLK * CELL);   // 125 KB
    int* counts_v = counts_u + NBKT * RBLK;                          // 125 KB

    float* OUT = (float*)d_out;
    unsigned short* B1 = (unsigned short*)d_out;               // cvt output; dead after hop 1
    unsigned short* B2 = (unsigned short*)recbuf_u;            // hop-2 output; recbuf dead after K2
                                                               // (12.8 MB <= 16.06 MB recbuf area)
    const dim3 blk(256);

    // K1: sg1 (65) + route (160) + cvt (6250)
    route_cvt_gemm1<<<65 + RBLK + 6250, blk, 0, stream>>>(edge_u, edge_v,
                                                          recbuf_u, counts_u, recbuf_v, counts_v,
                                                          (const float4*)X_v, (ushort4*)B1,
                                                          W0, b0, b1, W1, T);
    // K2: ELL build (392) + sg2 (65)
    ellbuild_sg2<<<2 * NBKT + 65, blk, 0, stream>>>(recbuf_u, counts_u, recbuf_v, counts_v,
                                                    ell_u, cnt_u, ell_v, cnt_v,
                                                    T, W2, P, PbT);
    // K3: hop 1 (v2u): A = S1*B1  + t_k
    gather1_tk<<<3125 + 196, blk, 0, stream>>>(B1, cnt_u, ell_u, A, cnt_v, ell_v, tbuf);
    // K4: hop 2 (u2v): B2 = S2*A  + g23   (B2 in ws so K5 can write OUT)
    gather2_g23<<<3125 + 196, blk, 0, stream>>>(A, cnt_v, ell_v, B2, cnt_u, ell_u, tbuf, g2, g3);
    // K5: fused hop 3 (v2u) + final MFMA GEMM + rank-3 bias epilogue
    gather3_gemm<<<782, blk, 0, stream>>>(B2, cnt_u, ell_u, PbT, P, b2, g2, g3, cnt_u, OUT);
}

// Round 5
// 247.093 us; speedup vs baseline: 1.0573x; 1.0573x over previous
//
#include <hip/hip_runtime.h>

#define D 128
#define NROW 50000      // N_U == N_V == 50000
#define NEDGE 640000
#define CAP 64          // ELL row capacity; P(Poisson(12.8) >= 64) ~ 3e-23/row

// edge routing geometry
#define RBLK 160        // route blocks; 160*4000 == 640000
#define EPB  4000       // edges per route block
#define NBKT 196        // row buckets of 256 rows: ceil(50000/256)
#define CELL 64         // per-(bucket, route-block) record capacity

typedef __attribute__((ext_vector_type(8))) short short8;
typedef __attribute__((ext_vector_type(4))) float f32x4;

__device__ __forceinline__ unsigned short f2bf(float f) {
    unsigned u = __float_as_uint(f);
    unsigned r = (u + 0x7fff + ((u >> 16) & 1)) >> 16;  // round-nearest-even
    return (unsigned short)r;
}
// accumulate packed bf16 pair (lo->e, hi->o)
__device__ __forceinline__ void acc2(float& e, float& o, unsigned g) {
    e += __uint_as_float(g << 16);
    o += __uint_as_float(g & 0xffff0000u);
}

// ============================================================
// K1 route_cvt_gemm1:
//   [0,65)     small_gemm1: T (130x128) = [W0; b0; b1] @ W1
//   [65,225)   route: bucket edges by row>>8 into per-(bucket,block)
//              segments via LDS atomics; coalesced 256B segment writes
//   [225,6475) cvt_bf16: B1 = bf16(X_v)  (fills CUs idle during route)
// ============================================================
__global__ __launch_bounds__(256) void route_cvt_gemm1(const int* __restrict__ eu,
                                                       const int* __restrict__ ev,
                                                       unsigned int* __restrict__ recbuf_u,
                                                       int* __restrict__ counts_u,
                                                       unsigned int* __restrict__ recbuf_v,
                                                       int* __restrict__ counts_v,
                                                       const float4* __restrict__ Xv4,
                                                       ushort4* __restrict__ Xb4,
                                                       const float* __restrict__ W0,
                                                       const float* __restrict__ b0,
                                                       const float* __restrict__ b1,
                                                       const float* __restrict__ W1,
                                                       float* __restrict__ T) {
    const int blk = blockIdx.x, tid = threadIdx.x;
    if (blk < 65) {                   // small_gemm1
        __shared__ float R[2][128];
        int sub = tid >> 7, j = tid & 127;
        int i = blk * 2 + sub;
        bool valid = (i < 130);
        const float* row = nullptr;
        if (valid && i < 128) row = W0 + i * D;
        else if (valid && i == 128) row = b0;
        R[sub][j] = row ? row[j] : 0.f;
        __syncthreads();
        if (!valid) return;
        if (i == 129) { T[129 * D + j] = b1[j]; return; }
        float acc = 0.f;
#pragma unroll 8
        for (int k = 0; k < 128; k++) acc += R[sub][k] * W1[k * D + j];
        T[i * D + j] = acc;
    } else if (blk < 225) {           // route
        __shared__ int cnt_s[NBKT];
        __shared__ unsigned int rec_s[NBKT * CELL];   // 49 KB
        const int rblk = blk - 65;
        const int base = rblk * EPB;
        for (int dir = 0; dir < 2; dir++) {
            const int* __restrict__ kk = dir ? ev : eu;   // key (destination row)
            const int* __restrict__ pp = dir ? eu : ev;   // payload (source row)
            unsigned int* __restrict__ recbuf = dir ? recbuf_v : recbuf_u;
            int* __restrict__ counts = dir ? counts_v : counts_u;
            if (tid < NBKT) cnt_s[tid] = 0;
            __syncthreads();
            for (int e0 = tid; e0 < EPB; e0 += 256) {
                int e = base + e0;
                int key = kk[e], pay = pp[e];
                int k = key >> 8;
                int p = atomicAdd(&cnt_s[k], 1);          // LDS atomic
                if (p < CELL) rec_s[k * CELL + p] = ((unsigned)key << 16) | (unsigned)pay;
            }
            __syncthreads();
            if (tid < NBKT) {
                int c = cnt_s[tid];
                counts[rblk * NBKT + tid] = (c < CELL) ? c : CELL;
            }
            const int wave = tid >> 6, lane = tid & 63;
            for (int k = wave; k < NBKT; k += 4) {        // 49 segments/wave
                int c = cnt_s[k]; c = (c < CELL) ? c : CELL;
                if (lane < c)
                    recbuf[(size_t)(k * RBLK + rblk) * CELL + lane] = rec_s[k * CELL + lane];
            }
            __syncthreads();
        }
    } else {                          // cvt: n4 = 1,600,000 = 6250*256 exactly
        int i = (blk - 225) * 256 + tid;
        float4 v = Xv4[i];
        ushort4 o;
        o.x = f2bf(v.x); o.y = f2bf(v.y); o.z = f2bf(v.z); o.w = f2bf(v.w);
        Xb4[i] = o;
    }
}

// ============================================================
// K2: ELL build (blocks [0,392)) + sg2 ([392,457))
// ============================================================
__global__ __launch_bounds__(256) void ellbuild_sg2(const unsigned int* __restrict__ recbuf_u,
                                                    const int* __restrict__ counts_u,
                                                    const unsigned int* __restrict__ recbuf_v,
                                                    const int* __restrict__ counts_v,
                                                    unsigned short* __restrict__ ell_u,
                                                    int* __restrict__ cnt_u,
                                                    unsigned short* __restrict__ ell_v,
                                                    int* __restrict__ cnt_v,
                                                    const float* __restrict__ T,
                                                    const float* __restrict__ W2,
                                                    float* __restrict__ P,
                                                    unsigned short* __restrict__ PbT) {
    const int blk = blockIdx.x, tid = threadIdx.x;
    if (blk < 2 * NBKT) {
        const int dir = (blk >= NBKT) ? 1 : 0;
        const int k = dir ? blk - NBKT : blk;
        const unsigned int* __restrict__ recbuf = dir ? recbuf_v : recbuf_u;
        const int* __restrict__ counts = dir ? counts_v : counts_u;
        unsigned short* __restrict__ ell = dir ? ell_v : ell_u;
        int* __restrict__ cnt = dir ? cnt_v : cnt_u;

        __shared__ __align__(16) unsigned short ell_s[256 * CAP];  // 32 KB
        __shared__ int cnt_s[256];
        __shared__ int seg_c[RBLK];
        cnt_s[tid] = 0;
        if (tid < RBLK) seg_c[tid] = counts[tid * NBKT + k];
        __syncthreads();

        const int wave = tid >> 6, lane = tid & 63;
        const unsigned int* rb = recbuf + (size_t)k * RBLK * CELL;
        int b = wave;
        int c0 = seg_c[b];
        unsigned int r0 = 0;
        if (lane < c0) r0 = rb[b * CELL + lane];
        while (b < RBLK) {
            int bn = b + 4;
            int c1 = 0; unsigned int r1 = 0;
            if (bn < RBLK) { c1 = seg_c[bn]; if (lane < c1) r1 = rb[bn * CELL + lane]; }
            if (lane < c0) {
                int lr = (r0 >> 16) & 255;                 // row within bucket
                int p = atomicAdd(&cnt_s[lr], 1);          // LDS atomic (exact degree)
                if (p < CAP) ell_s[lr * CAP + p] = (unsigned short)(r0 & 0xffff);
            }
            b = bn; c0 = c1; r0 = r1;
        }
        __syncthreads();
        const int row0 = k << 8;
        const int nrows = (row0 + 256 <= NROW) ? 256 : (NROW - row0);  // bucket 195: 80
        const uint4* src = (const uint4*)ell_s;
        uint4* dst = (uint4*)(ell + (size_t)row0 * CAP);
        for (int i = tid; i < nrows * 8; i += 256) dst[i] = src[i];    // coalesced 128B rows
        if (tid < nrows) cnt[row0 + tid] = cnt_s[tid];
    } else {                              // small_gemm2: P = T @ W2, PbT = bf16(P^T)
        __shared__ float R[2][128];
        int idx = blk - 2 * NBKT;
        int sub = tid >> 7, j = tid & 127;
        int i = idx * 2 + sub;
        bool valid = (i < 130);
        R[sub][j] = valid ? T[i * D + j] : 0.f;
        __syncthreads();
        if (!valid) return;
        float acc = 0.f;
#pragma unroll 8
        for (int kk = 0; kk < 128; kk++) acc += R[sub][kk] * W2[kk * D + j];
        P[i * D + j] = acc;
        if (i < 128) PbT[j * 128 + i] = f2bf(acc);
    }
}

// ============================================================
// gather core: one 16B output chunk (8 bf16 lanes) of
// sum_{s in idx[0..n)} A[s]. Ac = A + c*8 (chunk-offset base).
// Index reads vectorized (uint4 = 8 indices), 8 data loads in flight.
// ============================================================
__device__ __forceinline__ uint4 gather_chunk(const unsigned short* __restrict__ Ac,
                                              const unsigned short* __restrict__ idx,
                                              int n) {
    float a0 = 0.f, a1 = 0.f, a2 = 0.f, a3 = 0.f, a4 = 0.f, a5 = 0.f, a6 = 0.f, a7 = 0.f;
    int i = 0;
    for (; i + 8 <= n; i += 8) {
        uint4 iv = *(const uint4*)(idx + i);         // 8 indices, one load (16B aligned)
        uint4 q0 = *(const uint4*)(Ac + (size_t)(iv.x & 0xffffu) * D);
        uint4 q1 = *(const uint4*)(Ac + (size_t)(iv.x >> 16) * D);
        uint4 q2 = *(const uint4*)(Ac + (size_t)(iv.y & 0xffffu) * D);
        uint4 q3 = *(const uint4*)(Ac + (size_t)(iv.y >> 16) * D);
        uint4 q4 = *(const uint4*)(Ac + (size_t)(iv.z & 0xffffu) * D);
        uint4 q5 = *(const uint4*)(Ac + (size_t)(iv.z >> 16) * D);
        uint4 q6 = *(const uint4*)(Ac + (size_t)(iv.w & 0xffffu) * D);
        uint4 q7 = *(const uint4*)(Ac + (size_t)(iv.w >> 16) * D);
        acc2(a0, a1, q0.x); acc2(a2, a3, q0.y); acc2(a4, a5, q0.z); acc2(a6, a7, q0.w);
        acc2(a0, a1, q1.x); acc2(a2, a3, q1.y); acc2(a4, a5, q1.z); acc2(a6, a7, q1.w);
        acc2(a0, a1, q2.x); acc2(a2, a3, q2.y); acc2(a4, a5, q2.z); acc2(a6, a7, q2.w);
        acc2(a0, a1, q3.x); acc2(a2, a3, q3.y); acc2(a4, a5, q3.z); acc2(a6, a7, q3.w);
        acc2(a0, a1, q4.x); acc2(a2, a3, q4.y); acc2(a4, a5, q4.z); acc2(a6, a7, q4.w);
        acc2(a0, a1, q5.x); acc2(a2, a3, q5.y); acc2(a4, a5, q5.z); acc2(a6, a7, q5.w);
        acc2(a0, a1, q6.x); acc2(a2, a3, q6.y); acc2(a4, a5, q6.z); acc2(a6, a7, q6.w);
        acc2(a0, a1, q7.x); acc2(a2, a3, q7.y); acc2(a4, a5, q7.z); acc2(a6, a7, q7.w);
    }
    if (i + 4 <= n) {
        uint2 iv = *(const uint2*)(idx + i);         // 4 indices (8B aligned: i%8==0)
        uint4 q0 = *(const uint4*)(Ac + (size_t)(iv.x & 0xffffu) * D);
        uint4 q1 = *(const uint4*)(Ac + (size_t)(iv.x >> 16) * D);
        uint4 q2 = *(const uint4*)(Ac + (size_t)(iv.y & 0xffffu) * D);
        uint4 q3 = *(const uint4*)(Ac + (size_t)(iv.y >> 16) * D);
        acc2(a0, a1, q0.x); acc2(a2, a3, q0.y); acc2(a4, a5, q0.z); acc2(a6, a7, q0.w);
        acc2(a0, a1, q1.x); acc2(a2, a3, q1.y); acc2(a4, a5, q1.z); acc2(a6, a7, q1.w);
        acc2(a0, a1, q2.x); acc2(a2, a3, q2.y); acc2(a4, a5, q2.z); acc2(a6, a7, q2.w);
        acc2(a0, a1, q3.x); acc2(a2, a3, q3.y); acc2(a4, a5, q3.z); acc2(a6, a7, q3.w);
        i += 4;
    }
    for (; i < n; i++) {
        uint4 q0 = *(const uint4*)(Ac + (size_t)idx[i] * D);
        acc2(a0, a1, q0.x); acc2(a2, a3, q0.y); acc2(a4, a5, q0.z); acc2(a6, a7, q0.w);
    }
    uint4 o;
    o.x = (unsigned)f2bf(a0) | ((unsigned)f2bf(a1) << 16);
    o.y = (unsigned)f2bf(a2) | ((unsigned)f2bf(a3) << 16);
    o.z = (unsigned)f2bf(a4) | ((unsigned)f2bf(a5) << 16);
    o.w = (unsigned)f2bf(a6) | ((unsigned)f2bf(a7) << 16);
    return o;
}

// subwave-16 gather to global: OUTb[r] = bf16( sum_{s in ELL[r]} A[s] )
__device__ __forceinline__ void gather_body(const unsigned short* __restrict__ A,
                                            const int* __restrict__ cnt,
                                            const unsigned short* __restrict__ ell,
                                            unsigned short* __restrict__ OUTb,
                                            int blk) {
    const int r = blk * 16 + (threadIdx.x >> 4);    // 50000 % 16 == 0
    const int c = threadIdx.x & 15;                  // 16B chunk within row
    int n = cnt[r]; n = (n < CAP) ? n : CAP;
    uint4 o = gather_chunk(A + c * 8, ell + (size_t)r * CAP, n);
    *(uint4*)(OUTb + (size_t)r * D + c * 8) = o;
}

__device__ __forceinline__ void tk_body(const int* __restrict__ cnt_v,
                                        const unsigned short* __restrict__ ell_v,
                                        const int* __restrict__ cnt_u,
                                        int* __restrict__ t, int v) {
    if (v >= NROW) return;
    int n = cnt_v[v]; n = (n < CAP) ? n : CAP;
    const unsigned short* row = ell_v + (size_t)v * CAP;
    int s = 0;
    for (int i = 0; i < n; i += 8) {
        uint4 iv = *(const uint4*)(row + i);     // safe: row has CAP=64 entries
        unsigned sx[8] = {iv.x & 0xffffu, iv.x >> 16, iv.y & 0xffffu, iv.y >> 16,
                          iv.z & 0xffffu, iv.z >> 16, iv.w & 0xffffu, iv.w >> 16};
#pragma unroll
        for (int j = 0; j < 8; j++) if (i + j < n) s += cnt_u[sx[j]];
    }
    t[v] = s;
}

__device__ __forceinline__ void g23_body(const int* __restrict__ cnt_u,
                                         const unsigned short* __restrict__ ell_u,
                                         const int* __restrict__ cnt_v,
                                         const int* __restrict__ t,
                                         int* __restrict__ g2, int* __restrict__ g3, int u) {
    if (u >= NROW) return;
    int n = cnt_u[u]; n = (n < CAP) ? n : CAP;
    const unsigned short* row = ell_u + (size_t)u * CAP;
    int a = 0, b = 0;
    for (int i = 0; i < n; i += 8) {
        uint4 iv = *(const uint4*)(row + i);
        unsigned sx[8] = {iv.x & 0xffffu, iv.x >> 16, iv.y & 0xffffu, iv.y >> 16,
                          iv.z & 0xffffu, iv.z >> 16, iv.w & 0xffffu, iv.w >> 16};
#pragma unroll
        for (int j = 0; j < 8; j++)
            if (i + j < n) { a += t[sx[j]]; b += cnt_v[sx[j]]; }
    }
    g2[u] = a;
    g3[u] = b;
}

// K3: hop 1 (v2u) + t_k
__global__ __launch_bounds__(256) void gather1_tk(const unsigned short* __restrict__ A,
                                                  const int* __restrict__ cnt_u,
                                                  const unsigned short* __restrict__ ell_u,
                                                  unsigned short* __restrict__ OUTb,
                                                  const int* __restrict__ cnt_v,
                                                  const unsigned short* __restrict__ ell_v,
                                                  int* __restrict__ t) {
    if (blockIdx.x < 3125) gather_body(A, cnt_u, ell_u, OUTb, blockIdx.x);
    else tk_body(cnt_v, ell_v, cnt_u, t, (blockIdx.x - 3125) * 256 + threadIdx.x);
}

// K4: hop 2 (u2v) + g23
__global__ __launch_bounds__(256) void gather2_g23(const unsigned short* __restrict__ A,
                                                   const int* __restrict__ cnt_v,
                                                   const unsigned short* __restrict__ ell_v,
                                                   unsigned short* __restrict__ OUTb,
                                                   const int* __restrict__ cnt_u,
                                                   const unsigned short* __restrict__ ell_u,
                                                   const int* __restrict__ t,
                                                   int* __restrict__ g2, int* __restrict__ g3) {
    if (blockIdx.x < 3125) gather_body(A, cnt_v, ell_v, OUTb, blockIdx.x);
    else g23_body(cnt_u, ell_u, cnt_v, t, g2, g3, (blockIdx.x - 3125) * 256 + threadIdx.x);
}

// ============================================================
// K5: fused hop 3 (v2u) + MFMA final GEMM, hop-native geometry:
// 3125 blocks x 16 rows. Phase 1: each thread gathers ONE 16B chunk
// (identical work shape to the standalone hop). Phase 2: the 4 waves
// split the 16x128 output tile (2 n-tiles each, 8 MFMAs/wave).
// LSTRIDE=136 (272B row) keeps ds_read_b128 at free 2-way aliasing.
// OUT[r][j] = (Z @ W0W1W2)[r][j] + g2[r]*c0[j] + g3[r]*c1[j] + du[r]*b2[j]
// ============================================================
#define LSTRIDE 136   // ushorts per LDS row = 17 * 8 (272 B)

__global__ __launch_bounds__(256) void gather3_gemm(const unsigned short* __restrict__ B2,
                                                    const int* __restrict__ cnt_u,
                                                    const unsigned short* __restrict__ ell_u,
                                                    const unsigned short* __restrict__ PbT,
                                                    const float* __restrict__ P,
                                                    const float* __restrict__ b2,
                                                    const int* __restrict__ g2,
                                                    const int* __restrict__ g3,
                                                    const int* __restrict__ du,
                                                    float* __restrict__ OUT) {
    __shared__ __align__(16) unsigned short Asm[16 * LSTRIDE];   // 4.25 KB
    const int tid = threadIdx.x;
    const int r0blk = blockIdx.x * 16;                // 50000 = 3125*16 exactly

    // ---- phase 1: gather this block's 16 rows (bf16) into LDS ----
    {
        const int rl = tid >> 4;                      // 0..15
        const int c = tid & 15;                       // 16B chunk within row
        int r = r0blk + rl;
        int n = cnt_u[r]; n = (n < CAP) ? n : CAP;
        uint4 o = gather_chunk(B2 + c * 8, ell_u + (size_t)r * CAP, n);
        *(uint4*)(Asm + rl * LSTRIDE + c * 8) = o;
    }
    __syncthreads();

    // ---- phase 2: wave w computes n-tiles {2w, 2w+1} of the 16x128 tile ----
    const int wave = tid >> 6;
    const int lane = tid & 63;
    const int ml = lane & 15;      // m (A-row / D-col) index
    const int quad = lane >> 4;    // k-quad / D-row-quad

    const uint4* zr = (const uint4*)(Asm + (size_t)ml * LSTRIDE);

    f32x4 acc[2];
    acc[0] = (f32x4){0.f, 0.f, 0.f, 0.f};
    acc[1] = (f32x4){0.f, 0.f, 0.f, 0.f};

#pragma unroll
    for (int kc = 0; kc < 4; kc++) {
        short8 a = __builtin_bit_cast(short8, zr[kc * 4 + quad]);
#pragma unroll
        for (int j = 0; j < 2; j++) {
            int nt = wave * 2 + j;
            const uint4* br = (const uint4*)(PbT + (size_t)(nt * 16 + ml) * D);
            short8 b = __builtin_bit_cast(short8, br[kc * 4 + quad]);
            acc[j] = __builtin_amdgcn_mfma_f32_16x16x32_bf16(a, b, acc[j], 0, 0, 0);
        }
    }

    float sg2[4], sg3[4], sdu[4];
#pragma unroll
    for (int reg = 0; reg < 4; reg++) {
        int r = r0blk + quad * 4 + reg;
        sg2[reg] = (float)g2[r];
        sg3[reg] = (float)g3[r];
        sdu[reg] = (float)du[r];
    }
    const float* c0 = P + 128 * D;
    const float* c1 = P + 129 * D;
#pragma unroll
    for (int j = 0; j < 2; j++) {
        int col = (wave * 2 + j) * 16 + ml;
        float cc0 = c0[col], cc1 = c1[col], cb2 = b2[col];
#pragma unroll
        for (int reg = 0; reg < 4; reg++) {
            int r = r0blk + quad * 4 + reg;
            OUT[(size_t)r * D + col] = acc[j][reg] + sg2[reg] * cc0 + sg3[reg] * cc1 + sdu[reg] * cb2;
        }
    }
}

// ============================================================
extern "C" void kernel_launch(void* const* d_in, const int* in_sizes, int n_in,
                              void* d_out, int out_size, void* d_ws, size_t ws_size,
                              hipStream_t stream) {
    // 0=X_u(unused), 1=X_v, 2=edge_u, 3=edge_v, 4=W0, 5=b0, 6=W1, 7=b1, 8=W2, 9=b2
    const float* X_v = (const float*)d_in[1];
    const int* edge_u = (const int*)d_in[2];
    const int* edge_v = (const int*)d_in[3];
    const float* W0 = (const float*)d_in[4];
    const float* b0 = (const float*)d_in[5];
    const float* W1 = (const float*)d_in[6];
    const float* b1 = (const float*)d_in[7];
    const float* W2 = (const float*)d_in[8];
    const float* b2 = (const float*)d_in[9];

    // ---- ws layout (~43.1 MB) ----
    char* w = (char*)d_ws;
    unsigned short* A = (unsigned short*)w;                    // bf16 [NROW x 128] = 12.8 MB
    unsigned short* ell_u = (unsigned short*)(w + 12800000);   // NROW*CAP ushort = 6.4 MB
    unsigned short* ell_v = ell_u + (size_t)NROW * CAP;        // 6.4 MB
    int* cnt_u = (int*)(ell_v + (size_t)NROW * CAP);           // 50000 (exact degrees)
    int* cnt_v = cnt_u + NROW;                                 // 50000
    int* tbuf  = cnt_v + NROW;                                 // 50000
    int* g2    = tbuf + NROW;                                  // 50000
    int* g3    = g2 + NROW;                                    // 50000
    float* T   = (float*)(g3 + NROW);                          // 130*128
    float* P   = T + 130 * D;                                  // 130*128
    unsigned short* PbT = (unsigned short*)(P + 130 * D);      // 128*128 bf16
    unsigned int* recbuf_u = (unsigned int*)(PbT + 128 * 128); // 196*160*64 u32 = 8.03 MB
    unsigned int* recbuf_v = recbuf_u + (size_t)NBKT * RBLK * CELL;  // 8.03 MB
    int* counts_u = (int*)(recbuf_v + (size_t)NBKT * RBLK * CELL);   // 125 KB
    int* counts_v = counts_u + NBKT * RBLK;                          // 125 KB

    float* OUT = (float*)d_out;
    unsigned short* B1 = (unsigned short*)d_out;               // cvt output; dead after hop 1
    unsigned short* B2 = (unsigned short*)recbuf_u;            // hop-2 output; recbuf dead after K2
                                                               // (12.8 MB <= 16.06 MB recbuf area)
    const dim3 blk(256);

    // K1: sg1 (65) + route (160) + cvt (6250)
    route_cvt_gemm1<<<65 + RBLK + 6250, blk, 0, stream>>>(edge_u, edge_v,
                                                          recbuf_u, counts_u, recbuf_v, counts_v,
                                                          (const float4*)X_v, (ushort4*)B1,
                                                          W0, b0, b1, W1, T);
    // K2: ELL build (392) + sg2 (65)
    ellbuild_sg2<<<2 * NBKT + 65, blk, 0, stream>>>(recbuf_u, counts_u, recbuf_v, counts_v,
                                                    ell_u, cnt_u, ell_v, cnt_v,
                                                    T, W2, P, PbT);
    // K3: hop 1 (v2u): A = S1*B1  + t_k
    gather1_tk<<<3125 + 196, blk, 0, stream>>>(B1, cnt_u, ell_u, A, cnt_v, ell_v, tbuf);
    // K4: hop 2 (u2v): B2 = S2*A  + g23   (B2 in ws so K5 can write OUT)
    gather2_g23<<<3125 + 196, blk, 0, stream>>>(A, cnt_v, ell_v, B2, cnt_u, ell_u, tbuf, g2, g3);
    // K5: fused hop 3 (v2u) + final MFMA GEMM at hop-native 3125-block geometry
    gather3_gemm<<<3125, blk, 0, stream>>>(B2, cnt_u, ell_u, PbT, P, b2, g2, g3, cnt_u, OUT);
}

// Round 6
// 243.856 us; speedup vs baseline: 1.0713x; 1.0133x over previous
//
#include <hip/hip_runtime.h>

#define D 128
#define NROW 50000      // N_U == N_V == 50000
#define NEDGE 640000
#define CAP 64          // ELL row capacity; P(Poisson(12.8) >= 64) ~ 3e-23/row
#define ZROW 50000      // zero-row index (tables have NROW+1 rows; row ZROW is all-zero)

// edge routing geometry
#define RBLK 160        // route blocks; 160*4000 == 640000
#define EPB  4000       // edges per route block
#define NBKT 196        // row buckets of 256 rows: ceil(50000/256)
#define CELL 64         // per-(bucket, route-block) record capacity

typedef __attribute__((ext_vector_type(8))) short short8;
typedef __attribute__((ext_vector_type(4))) float f32x4;

__device__ __forceinline__ unsigned short f2bf(float f) {
    unsigned u = __float_as_uint(f);
    unsigned r = (u + 0x7fff + ((u >> 16) & 1)) >> 16;  // round-nearest-even
    return (unsigned short)r;
}
// accumulate packed bf16 pair (lo->e, hi->o)
__device__ __forceinline__ void acc2(float& e, float& o, unsigned g) {
    e += __uint_as_float(g << 16);
    o += __uint_as_float(g & 0xffff0000u);
}

// ============================================================
// K1 route_cvt_gemm1:
//   [0,65)     small_gemm1: T (130x128) = [W0; b0; b1] @ W1
//   [65,225)   route: bucket edges by row>>8 into per-(bucket,block)
//              segments via LDS atomics; coalesced 256B segment writes
//   [225,6475) cvt_bf16: B1 = bf16(X_v)  (fills CUs idle during route)
// ============================================================
__global__ __launch_bounds__(256) void route_cvt_gemm1(const int* __restrict__ eu,
                                                       const int* __restrict__ ev,
                                                       unsigned int* __restrict__ recbuf_u,
                                                       int* __restrict__ counts_u,
                                                       unsigned int* __restrict__ recbuf_v,
                                                       int* __restrict__ counts_v,
                                                       const float4* __restrict__ Xv4,
                                                       ushort4* __restrict__ Xb4,
                                                       const float* __restrict__ W0,
                                                       const float* __restrict__ b0,
                                                       const float* __restrict__ b1,
                                                       const float* __restrict__ W1,
                                                       float* __restrict__ T) {
    const int blk = blockIdx.x, tid = threadIdx.x;
    if (blk < 65) {                   // small_gemm1
        __shared__ float R[2][128];
        int sub = tid >> 7, j = tid & 127;
        int i = blk * 2 + sub;
        bool valid = (i < 130);
        const float* row = nullptr;
        if (valid && i < 128) row = W0 + i * D;
        else if (valid && i == 128) row = b0;
        R[sub][j] = row ? row[j] : 0.f;
        __syncthreads();
        if (!valid) return;
        if (i == 129) { T[129 * D + j] = b1[j]; return; }
        float acc = 0.f;
#pragma unroll 8
        for (int k = 0; k < 128; k++) acc += R[sub][k] * W1[k * D + j];
        T[i * D + j] = acc;
    } else if (blk < 225) {           // route
        __shared__ int cnt_s[NBKT];
        __shared__ unsigned int rec_s[NBKT * CELL];   // 49 KB
        const int rblk = blk - 65;
        const int base = rblk * EPB;
        for (int dir = 0; dir < 2; dir++) {
            const int* __restrict__ kk = dir ? ev : eu;   // key (destination row)
            const int* __restrict__ pp = dir ? eu : ev;   // payload (source row)
            unsigned int* __restrict__ recbuf = dir ? recbuf_v : recbuf_u;
            int* __restrict__ counts = dir ? counts_v : counts_u;
            if (tid < NBKT) cnt_s[tid] = 0;
            __syncthreads();
            for (int e0 = tid; e0 < EPB; e0 += 256) {
                int e = base + e0;
                int key = kk[e], pay = pp[e];
                int k = key >> 8;
                int p = atomicAdd(&cnt_s[k], 1);          // LDS atomic
                if (p < CELL) rec_s[k * CELL + p] = ((unsigned)key << 16) | (unsigned)pay;
            }
            __syncthreads();
            if (tid < NBKT) {
                int c = cnt_s[tid];
                counts[rblk * NBKT + tid] = (c < CELL) ? c : CELL;
            }
            const int wave = tid >> 6, lane = tid & 63;
            for (int k = wave; k < NBKT; k += 4) {        // 49 segments/wave
                int c = cnt_s[k]; c = (c < CELL) ? c : CELL;
                if (lane < c)
                    recbuf[(size_t)(k * RBLK + rblk) * CELL + lane] = rec_s[k * CELL + lane];
            }
            __syncthreads();
        }
    } else {                          // cvt: n4 = 1,600,000 = 6250*256 exactly
        int i = (blk - 225) * 256 + tid;
        float4 v = Xv4[i];
        ushort4 o;
        o.x = f2bf(v.x); o.y = f2bf(v.y); o.z = f2bf(v.z); o.w = f2bf(v.w);
        Xb4[i] = o;
    }
}

// ============================================================
// K2: ELL build (blocks [0,392)) + sg2 ([392,457)) + zero-rows (457)
// ELL build: 4-deep segment prefetch; slack slots filled with ZROW so
// gathers are tail-free (slack loads hit the L2-hot zero row).
// ============================================================
__global__ __launch_bounds__(256) void ellbuild_sg2(const unsigned int* __restrict__ recbuf_u,
                                                    const int* __restrict__ counts_u,
                                                    const unsigned int* __restrict__ recbuf_v,
                                                    const int* __restrict__ counts_v,
                                                    unsigned short* __restrict__ ell_u,
                                                    int* __restrict__ cnt_u,
                                                    unsigned short* __restrict__ ell_v,
                                                    int* __restrict__ cnt_v,
                                                    const float* __restrict__ T,
                                                    const float* __restrict__ W2,
                                                    float* __restrict__ P,
                                                    unsigned short* __restrict__ PbT,
                                                    unsigned short* __restrict__ zrowB1,
                                                    unsigned short* __restrict__ zrowA) {
    const int blk = blockIdx.x, tid = threadIdx.x;
    if (blk < 2 * NBKT) {
        const int dir = (blk >= NBKT) ? 1 : 0;
        const int k = dir ? blk - NBKT : blk;
        const unsigned int* __restrict__ recbuf = dir ? recbuf_v : recbuf_u;
        const int* __restrict__ counts = dir ? counts_v : counts_u;
        unsigned short* __restrict__ ell = dir ? ell_v : ell_u;
        int* __restrict__ cnt = dir ? cnt_v : cnt_u;

        __shared__ __align__(16) unsigned short ell_s[256 * CAP];  // 32 KB
        __shared__ int cnt_s[256];
        __shared__ int seg_c[RBLK];
        cnt_s[tid] = 0;
        if (tid < RBLK) seg_c[tid] = counts[tid * NBKT + k];
        {   // fill slack with ZROW (0xC350) so unwritten slots point at the zero row
            const uint4 fv = {0xC350C350u, 0xC350C350u, 0xC350C350u, 0xC350C350u};
            uint4* es4 = (uint4*)ell_s;                  // 2048 uint4
            for (int i = tid; i < 2048; i += 256) es4[i] = fv;
        }
        __syncthreads();

        const int wave = tid >> 6, lane = tid & 63;
        const unsigned int* rb = recbuf + (size_t)k * RBLK * CELL;
        // 4-deep software pipeline over this wave's segments (b = wave, wave+4, ...)
        int cc0, cc1, cc2; unsigned int rr0, rr1, rr2;
        int b = wave;
#define LOADSEG(cc, rr, bs) { int _b = (bs); cc = (_b < RBLK) ? seg_c[_b] : 0; rr = 0u; \
                              if (lane < cc) rr = rb[(size_t)_b * CELL + lane]; }
        LOADSEG(cc0, rr0, b)
        LOADSEG(cc1, rr1, b + 4)
        LOADSEG(cc2, rr2, b + 8)
        while (b < RBLK) {
            if (lane < cc0) {
                int lr = (rr0 >> 16) & 255;                // row within bucket
                int p = atomicAdd(&cnt_s[lr], 1);          // LDS atomic (exact degree)
                if (p < CAP) ell_s[lr * CAP + p] = (unsigned short)(rr0 & 0xffff);
            }
            cc0 = cc1; rr0 = rr1; cc1 = cc2; rr1 = rr2;
            LOADSEG(cc2, rr2, b + 12)
            b += 4;
        }
#undef LOADSEG
        __syncthreads();
        const int row0 = k << 8;
        const int nrows = (row0 + 256 <= NROW) ? 256 : (NROW - row0);  // bucket 195: 80
        const uint4* src = (const uint4*)ell_s;
        uint4* dst = (uint4*)(ell + (size_t)row0 * CAP);
        for (int i = tid; i < nrows * 8; i += 256) dst[i] = src[i];    // coalesced 128B rows
        if (tid < nrows) cnt[row0 + tid] = cnt_s[tid];
    } else if (blk < 2 * NBKT + 65) {     // small_gemm2: P = T @ W2, PbT = bf16(P^T)
        __shared__ float R[2][128];
        int idx = blk - 2 * NBKT;
        int sub = tid >> 7, j = tid & 127;
        int i = idx * 2 + sub;
        bool valid = (i < 130);
        R[sub][j] = valid ? T[i * D + j] : 0.f;
        __syncthreads();
        if (!valid) return;
        float acc = 0.f;
#pragma unroll 8
        for (int kk = 0; kk < 128; kk++) acc += R[sub][kk] * W2[kk * D + j];
        P[i * D + j] = acc;
        if (i < 128) PbT[j * 128 + i] = f2bf(acc);
    } else {                              // zero-rows for B1 and A (row ZROW)
        const uint4 z = {0u, 0u, 0u, 0u};
        if (tid < 16) ((uint4*)zrowB1)[tid] = z;
        else if (tid < 32) ((uint4*)zrowA)[tid - 16] = z;
    }
}

// ============================================================
// gather core (tail-free): one 16B output chunk (8 bf16 lanes) of
// sum_{s in idx[0..n)} A[s]. Slack slots hold ZROW -> zero row (exact +0).
// Index reads vectorized (uint4 = 8 indices), 8 data loads in flight.
// ============================================================
__device__ __forceinline__ uint4 gather_chunk(const unsigned short* __restrict__ Ac,
                                              const unsigned short* __restrict__ idx,
                                              int n) {
    float a0 = 0.f, a1 = 0.f, a2 = 0.f, a3 = 0.f, a4 = 0.f, a5 = 0.f, a6 = 0.f, a7 = 0.f;
    for (int i = 0; i < n; i += 8) {
        uint4 iv = *(const uint4*)(idx + i);         // 8 indices, one load (16B aligned)
        uint4 q0 = *(const uint4*)(Ac + (size_t)(iv.x & 0xffffu) * D);
        uint4 q1 = *(const uint4*)(Ac + (size_t)(iv.x >> 16) * D);
        uint4 q2 = *(const uint4*)(Ac + (size_t)(iv.y & 0xffffu) * D);
        uint4 q3 = *(const uint4*)(Ac + (size_t)(iv.y >> 16) * D);
        uint4 q4 = *(const uint4*)(Ac + (size_t)(iv.z & 0xffffu) * D);
        uint4 q5 = *(const uint4*)(Ac + (size_t)(iv.z >> 16) * D);
        uint4 q6 = *(const uint4*)(Ac + (size_t)(iv.w & 0xffffu) * D);
        uint4 q7 = *(const uint4*)(Ac + (size_t)(iv.w >> 16) * D);
        acc2(a0, a1, q0.x); acc2(a2, a3, q0.y); acc2(a4, a5, q0.z); acc2(a6, a7, q0.w);
        acc2(a0, a1, q1.x); acc2(a2, a3, q1.y); acc2(a4, a5, q1.z); acc2(a6, a7, q1.w);
        acc2(a0, a1, q2.x); acc2(a2, a3, q2.y); acc2(a4, a5, q2.z); acc2(a6, a7, q2.w);
        acc2(a0, a1, q3.x); acc2(a2, a3, q3.y); acc2(a4, a5, q3.z); acc2(a6, a7, q3.w);
        acc2(a0, a1, q4.x); acc2(a2, a3, q4.y); acc2(a4, a5, q4.z); acc2(a6, a7, q4.w);
        acc2(a0, a1, q5.x); acc2(a2, a3, q5.y); acc2(a4, a5, q5.z); acc2(a6, a7, q5.w);
        acc2(a0, a1, q6.x); acc2(a2, a3, q6.y); acc2(a4, a5, q6.z); acc2(a6, a7, q6.w);
        acc2(a0, a1, q7.x); acc2(a2, a3, q7.y); acc2(a4, a5, q7.z); acc2(a6, a7, q7.w);
    }
    uint4 o;
    o.x = (unsigned)f2bf(a0) | ((unsigned)f2bf(a1) << 16);
    o.y = (unsigned)f2bf(a2) | ((unsigned)f2bf(a3) << 16);
    o.z = (unsigned)f2bf(a4) | ((unsigned)f2bf(a5) << 16);
    o.w = (unsigned)f2bf(a6) | ((unsigned)f2bf(a7) << 16);
    return o;
}

// subwave-16 gather to global: OUTb[r] = bf16( sum_{s in ELL[r]} A[s] )
__device__ __forceinline__ void gather_body(const unsigned short* __restrict__ A,
                                            const int* __restrict__ cnt,
                                            const unsigned short* __restrict__ ell,
                                            unsigned short* __restrict__ OUTb,
                                            int blk) {
    const int r = blk * 16 + (threadIdx.x >> 4);    // 50000 % 16 == 0
    const int c = threadIdx.x & 15;                  // 16B chunk within row
    int n = cnt[r]; n = (n < CAP) ? n : CAP;
    uint4 o = gather_chunk(A + c * 8, ell + (size_t)r * CAP, n);
    *(uint4*)(OUTb + (size_t)r * D + c * 8) = o;
}

__device__ __forceinline__ void tk_body(const int* __restrict__ cnt_v,
                                        const unsigned short* __restrict__ ell_v,
                                        const int* __restrict__ cnt_u,
                                        int* __restrict__ t, int v) {
    if (v >= NROW) return;
    int n = cnt_v[v]; n = (n < CAP) ? n : CAP;
    const unsigned short* row = ell_v + (size_t)v * CAP;
    int s = 0;
    for (int i = 0; i < n; i += 8) {
        uint4 iv = *(const uint4*)(row + i);     // safe: row has CAP=64 entries
        unsigned sx[8] = {iv.x & 0xffffu, iv.x >> 16, iv.y & 0xffffu, iv.y >> 16,
                          iv.z & 0xffffu, iv.z >> 16, iv.w & 0xffffu, iv.w >> 16};
#pragma unroll
        for (int j = 0; j < 8; j++) if (i + j < n) s += cnt_u[sx[j]];
    }
    t[v] = s;
}

__device__ __forceinline__ void g23_body(const int* __restrict__ cnt_u,
                                         const unsigned short* __restrict__ ell_u,
                                         const int* __restrict__ cnt_v,
                                         const int* __restrict__ t,
                                         int* __restrict__ g2, int* __restrict__ g3, int u) {
    if (u >= NROW) return;
    int n = cnt_u[u]; n = (n < CAP) ? n : CAP;
    const unsigned short* row = ell_u + (size_t)u * CAP;
    int a = 0, b = 0;
    for (int i = 0; i < n; i += 8) {
        uint4 iv = *(const uint4*)(row + i);
        unsigned sx[8] = {iv.x & 0xffffu, iv.x >> 16, iv.y & 0xffffu, iv.y >> 16,
                          iv.z & 0xffffu, iv.z >> 16, iv.w & 0xffffu, iv.w >> 16};
#pragma unroll
        for (int j = 0; j < 8; j++)
            if (i + j < n) { a += t[sx[j]]; b += cnt_v[sx[j]]; }
    }
    g2[u] = a;
    g3[u] = b;
}

// K3: hop 1 (v2u) + t_k + zero-row for B2 (block 3321)
__global__ __launch_bounds__(256) void gather1_tk(const unsigned short* __restrict__ A,
                                                  const int* __restrict__ cnt_u,
                                                  const unsigned short* __restrict__ ell_u,
                                                  unsigned short* __restrict__ OUTb,
                                                  const int* __restrict__ cnt_v,
                                                  const unsigned short* __restrict__ ell_v,
                                                  int* __restrict__ t,
                                                  unsigned short* __restrict__ zrowB2) {
    if (blockIdx.x < 3125) { gather_body(A, cnt_u, ell_u, OUTb, blockIdx.x); return; }
    int vblk = blockIdx.x - 3125;
    if (vblk == 196) {
        const uint4 z = {0u, 0u, 0u, 0u};
        if (threadIdx.x < 16) ((uint4*)zrowB2)[threadIdx.x] = z;
        return;
    }
    tk_body(cnt_v, ell_v, cnt_u, t, vblk * 256 + threadIdx.x);
}

// K4: hop 2 (u2v) + g23
__global__ __launch_bounds__(256) void gather2_g23(const unsigned short* __restrict__ A,
                                                   const int* __restrict__ cnt_v,
                                                   const unsigned short* __restrict__ ell_v,
                                                   unsigned short* __restrict__ OUTb,
                                                   const int* __restrict__ cnt_u,
                                                   const unsigned short* __restrict__ ell_u,
                                                   const int* __restrict__ t,
                                                   int* __restrict__ g2, int* __restrict__ g3) {
    if (blockIdx.x < 3125) gather_body(A, cnt_v, ell_v, OUTb, blockIdx.x);
    else g23_body(cnt_u, ell_u, cnt_v, t, g2, g3, (blockIdx.x - 3125) * 256 + threadIdx.x);
}

// ============================================================
// K5: fused hop 3 (v2u) + MFMA final GEMM, hop-native geometry:
// 3125 blocks x 16 rows. Phase 1: each thread gathers ONE 16B chunk.
// Phase 2: the 4 waves split the 16x128 output tile (2 n-tiles each).
// LSTRIDE=136 (272B row) keeps ds_read_b128 at free 2-way aliasing.
// OUT[r][j] = (Z @ W0W1W2)[r][j] + g2[r]*c0[j] + g3[r]*c1[j] + du[r]*b2[j]
// ============================================================
#define LSTRIDE 136   // ushorts per LDS row = 17 * 8 (272 B)

__global__ __launch_bounds__(256) void gather3_gemm(const unsigned short* __restrict__ B2,
                                                    const int* __restrict__ cnt_u,
                                                    const unsigned short* __restrict__ ell_u,
                                                    const unsigned short* __restrict__ PbT,
                                                    const float* __restrict__ P,
                                                    const float* __restrict__ b2,
                                                    const int* __restrict__ g2,
                                                    const int* __restrict__ g3,
                                                    const int* __restrict__ du,
                                                    float* __restrict__ OUT) {
    __shared__ __align__(16) unsigned short Asm[16 * LSTRIDE];   // 4.25 KB
    const int tid = threadIdx.x;
    const int r0blk = blockIdx.x * 16;                // 50000 = 3125*16 exactly

    // ---- phase 1: gather this block's 16 rows (bf16) into LDS ----
    {
        const int rl = tid >> 4;                      // 0..15
        const int c = tid & 15;                       // 16B chunk within row
        int r = r0blk + rl;
        int n = cnt_u[r]; n = (n < CAP) ? n : CAP;
        uint4 o = gather_chunk(B2 + c * 8, ell_u + (size_t)r * CAP, n);
        *(uint4*)(Asm + rl * LSTRIDE + c * 8) = o;
    }
    __syncthreads();

    // ---- phase 2: wave w computes n-tiles {2w, 2w+1} of the 16x128 tile ----
    const int wave = tid >> 6;
    const int lane = tid & 63;
    const int ml = lane & 15;      // m (A-row / D-col) index
    const int quad = lane >> 4;    // k-quad / D-row-quad

    const uint4* zr = (const uint4*)(Asm + (size_t)ml * LSTRIDE);

    f32x4 acc[2];
    acc[0] = (f32x4){0.f, 0.f, 0.f, 0.f};
    acc[1] = (f32x4){0.f, 0.f, 0.f, 0.f};

#pragma unroll
    for (int kc = 0; kc < 4; kc++) {
        short8 a = __builtin_bit_cast(short8, zr[kc * 4 + quad]);
#pragma unroll
        for (int j = 0; j < 2; j++) {
            int nt = wave * 2 + j;
            const uint4* br = (const uint4*)(PbT + (size_t)(nt * 16 + ml) * D);
            short8 b = __builtin_bit_cast(short8, br[kc * 4 + quad]);
            acc[j] = __builtin_amdgcn_mfma_f32_16x16x32_bf16(a, b, acc[j], 0, 0, 0);
        }
    }

    float sg2[4], sg3[4], sdu[4];
#pragma unroll
    for (int reg = 0; reg < 4; reg++) {
        int r = r0blk + quad * 4 + reg;
        sg2[reg] = (float)g2[r];
        sg3[reg] = (float)g3[r];
        sdu[reg] = (float)du[r];
    }
    const float* c0 = P + 128 * D;
    const float* c1 = P + 129 * D;
#pragma unroll
    for (int j = 0; j < 2; j++) {
        int col = (wave * 2 + j) * 16 + ml;
        float cc0 = c0[col], cc1 = c1[col], cb2 = b2[col];
#pragma unroll
        for (int reg = 0; reg < 4; reg++) {
            int r = r0blk + quad * 4 + reg;
            OUT[(size_t)r * D + col] = acc[j][reg] + sg2[reg] * cc0 + sg3[reg] * cc1 + sdu[reg] * cb2;
        }
    }
}

// ============================================================
extern "C" void kernel_launch(void* const* d_in, const int* in_sizes, int n_in,
                              void* d_out, int out_size, void* d_ws, size_t ws_size,
                              hipStream_t stream) {
    // 0=X_u(unused), 1=X_v, 2=edge_u, 3=edge_v, 4=W0, 5=b0, 6=W1, 7=b1, 8=W2, 9=b2
    const float* X_v = (const float*)d_in[1];
    const int* edge_u = (const int*)d_in[2];
    const int* edge_v = (const int*)d_in[3];
    const float* W0 = (const float*)d_in[4];
    const float* b0 = (const float*)d_in[5];
    const float* W1 = (const float*)d_in[6];
    const float* b1 = (const float*)d_in[7];
    const float* W2 = (const float*)d_in[8];
    const float* b2 = (const float*)d_in[9];

    // ---- ws layout (~43.1 MB); A has NROW+1 rows (row ZROW = zeros) ----
    char* w = (char*)d_ws;
    unsigned short* A = (unsigned short*)w;                    // bf16 [(NROW+1) x 128] = 12.80 MB
    unsigned short* ell_u = (unsigned short*)(w + 12800256);   // NROW*CAP ushort = 6.4 MB
    unsigned short* ell_v = ell_u + (size_t)NROW * CAP;        // 6.4 MB
    int* cnt_u = (int*)(ell_v + (size_t)NROW * CAP);           // 50000 (exact degrees)
    int* cnt_v = cnt_u + NROW;                                 // 50000
    int* tbuf  = cnt_v + NROW;                                 // 50000
    int* g2    = tbuf + NROW;                                  // 50000
    int* g3    = g2 + NROW;                                    // 50000
    float* T   = (float*)(g3 + NROW);                          // 130*128
    float* P   = T + 130 * D;                                  // 130*128
    unsigned short* PbT = (unsigned short*)(P + 130 * D);      // 128*128 bf16
    unsigned int* recbuf_u = (unsigned int*)(PbT + 128 * 128); // 196*160*64 u32 = 8.03 MB
    unsigned int* recbuf_v = recbuf_u + (size_t)NBKT * RBLK * CELL;  // 8.03 MB
    int* counts_u = (int*)(recbuf_v + (size_t)NBKT * RBLK * CELL);   // 125 KB
    int* counts_v = counts_u + NBKT * RBLK;                          // 125 KB

    float* OUT = (float*)d_out;
    unsigned short* B1 = (unsigned short*)d_out;               // cvt output; dead after hop 1
                                                               // (rows 0..NROW fit in 25.6 MB out)
    unsigned short* B2 = (unsigned short*)recbuf_u;            // hop-2 output; recbuf dead after K2
                                                               // ((NROW+1)*256B = 12.80 MB <= 16.06 MB)
    unsigned short* zrowB1 = B1 + (size_t)ZROW * D;
    unsigned short* zrowA  = A  + (size_t)ZROW * D;
    unsigned short* zrowB2 = B2 + (size_t)ZROW * D;

    const dim3 blk(256);

    // K1: sg1 (65) + route (160) + cvt (6250)
    route_cvt_gemm1<<<65 + RBLK + 6250, blk, 0, stream>>>(edge_u, edge_v,
                                                          recbuf_u, counts_u, recbuf_v, counts_v,
                                                          (const float4*)X_v, (ushort4*)B1,
                                                          W0, b0, b1, W1, T);
    // K2: ELL build (392) + sg2 (65) + zero-rows B1/A (1)
    ellbuild_sg2<<<2 * NBKT + 65 + 1, blk, 0, stream>>>(recbuf_u, counts_u, recbuf_v, counts_v,
                                                        ell_u, cnt_u, ell_v, cnt_v,
                                                        T, W2, P, PbT, zrowB1, zrowA);
    // K3: hop 1 (v2u): A = S1*B1  + t_k  + zero-row B2 (1)
    gather1_tk<<<3125 + 196 + 1, blk, 0, stream>>>(B1, cnt_u, ell_u, A, cnt_v, ell_v, tbuf, zrowB2);
    // K4: hop 2 (u2v): B2 = S2*A  + g23
    gather2_g23<<<3125 + 196, blk, 0, stream>>>(A, cnt_v, ell_v, B2, cnt_u, ell_u, tbuf, g2, g3);
    // K5: fused hop 3 (v2u) + final MFMA GEMM at hop-native 3125-block geometry
    gather3_gemm<<<3125, blk, 0, stream>>>(B2, cnt_u, ell_u, PbT, P, b2, g2, g3, cnt_u, OUT);
}